// Round 2
// baseline (3468.939 us; speedup 1.0000x reference)
//
#include <hip/hip_runtime.h>
#include <math.h>

constexpr int B_ = 4, S_ = 2048, E_ = 1024, H_ = 16, D_ = 64;
constexpr int M_ = B_ * S_;   // 8192 rows of x
constexpr int N3 = 3 * E_;    // 3072 qkv cols

// ---------------------------------------------------------------------------
// Kernel 1: qkv = x @ w_qkv + b_qkv, scattered into Q/K/V in [B,H,S,D] layout.
// 64x64 tile, BK=16, 256 threads, 4x4 micro-tile per thread. fp32.
// Each block maps to exactly one (t∈{q,k,v}, h) because BN == D == 64.
// ---------------------------------------------------------------------------
__global__ __launch_bounds__(256)
void qkv_kernel(const float* __restrict__ x, const float* __restrict__ w,
                const float* __restrict__ bias,
                float* __restrict__ Qb, float* __restrict__ Kb,
                float* __restrict__ Vb) {
    constexpr int BM = 64, BN = 64, BK = 16;
    __shared__ float As[BK][BM + 4];   // A stored transposed: As[k][m]
    __shared__ float Bs[BK][BN + 4];
    const int bn = blockIdx.x * BN;
    const int bm = blockIdx.y * BM;
    const int tid = threadIdx.x;
    const int tr = tid >> 4, tc = tid & 15;

    float acc[4][4] = {};
    for (int k0 = 0; k0 < E_; k0 += BK) {
        {   // A tile 64x16: one float4 per thread, stored transposed
            int m  = tid >> 2;
            int k4 = (tid & 3) << 2;
            float4 a = *reinterpret_cast<const float4*>(
                &x[(size_t)(bm + m) * E_ + k0 + k4]);
            As[k4 + 0][m] = a.x; As[k4 + 1][m] = a.y;
            As[k4 + 2][m] = a.z; As[k4 + 3][m] = a.w;
        }
        {   // B tile 16x64: one float4 per thread
            int k  = tid >> 4;
            int n4 = (tid & 15) << 2;
            float4 b = *reinterpret_cast<const float4*>(
                &w[(size_t)(k0 + k) * N3 + bn + n4]);
            *reinterpret_cast<float4*>(&Bs[k][n4]) = b;
        }
        __syncthreads();
#pragma unroll
        for (int k = 0; k < BK; ++k) {
            float4 a4 = *reinterpret_cast<const float4*>(&As[k][tr * 4]);
            float4 b4 = *reinterpret_cast<const float4*>(&Bs[k][tc * 4]);
            float av[4] = {a4.x, a4.y, a4.z, a4.w};
            float bv[4] = {b4.x, b4.y, b4.z, b4.w};
#pragma unroll
            for (int i = 0; i < 4; ++i)
#pragma unroll
                for (int j = 0; j < 4; ++j)
                    acc[i][j] = fmaf(av[i], bv[j], acc[i][j]);
        }
        __syncthreads();
    }

    // epilogue: scatter. Whole block is one (t, h); d = n - bn.
    const int t = bn / E_;
    const int h = (bn % E_) >> 6;
    float* dst = (t == 0) ? Qb : (t == 1) ? Kb : Vb;
    const int b  = bm / S_;
    const int s0 = bm % S_;
    const size_t base = ((size_t)(b * H_ + h) * S_ + s0) * D_;
    float4 bias4 = *reinterpret_cast<const float4*>(&bias[bn + tc * 4]);
#pragma unroll
    for (int i = 0; i < 4; ++i) {
        int r = tr * 4 + i;
        float4 o;
        o.x = acc[i][0] + bias4.x; o.y = acc[i][1] + bias4.y;
        o.z = acc[i][2] + bias4.z; o.w = acc[i][3] + bias4.w;
        *reinterpret_cast<float4*>(&dst[base + (size_t)r * D_ + tc * 4]) = o;
    }
}

// ---------------------------------------------------------------------------
// Kernel 2: causal attention per (b, h, 64-row q-tile). Two passes over k:
//   pass 1: online row max m and denom l
//   pass 2: recompute scores, write normalized weights, accumulate PV -> ctx
// Upper-triangle tiles are written as exact zeros (matches fp32 underflow of
// exp(-10000 - m)). ctx is [B,S,E] merged-head layout.
// ---------------------------------------------------------------------------
__global__ __launch_bounds__(256)
void attn_kernel(const float* __restrict__ Qb, const float* __restrict__ Kb,
                 const float* __restrict__ Vb, float* __restrict__ wts,
                 float* __restrict__ ctx) {
    constexpr int BQ = 64, BKV = 64;
    __shared__ float Qt[D_][BQ + 4];    // transposed: Qt[d][q]
    __shared__ float Kt[D_][BKV + 4];   // transposed: Kt[d][k]
    __shared__ float Vs[BKV][D_ + 4];   // straight:   Vs[k][d]
    __shared__ float sc[BQ][BKV + 4];   // score / weight tile
    __shared__ float mrow[BQ], lrow[BQ];

    const int qt = blockIdx.x, h = blockIdx.y, b = blockIdx.z;
    const int q0 = qt * BQ;
    const int tid = threadIdx.x;
    const int tr = tid >> 4, tc = tid & 15;

    const size_t headbase = (size_t)(b * H_ + h) * S_ * D_;
    const float* Qh = Qb + headbase;
    const float* Kh = Kb + headbase;
    const float* Vh = Vb + headbase;
    float* wrow = wts + ((size_t)(b * H_ + h) * S_ + q0) * S_;

    // load Q tile (transposed into LDS)
#pragma unroll
    for (int i = 0; i < 4; ++i) {
        int idx = tid + i * 256;         // float4 index over 64x64 tile
        int row = idx >> 4;
        int c4  = (idx & 15) << 2;
        float4 v = *reinterpret_cast<const float4*>(
            &Qh[(size_t)(q0 + row) * D_ + c4]);
        Qt[c4 + 0][row] = v.x; Qt[c4 + 1][row] = v.y;
        Qt[c4 + 2][row] = v.z; Qt[c4 + 3][row] = v.w;
    }
    if (tid < BQ) { mrow[tid] = -INFINITY; lrow[tid] = 0.f; }
    __syncthreads();

    const int nkt = qt + 1;   // k-tiles at/below the diagonal

    // ---------------- pass 1: row max + denom ----------------
    for (int kt = 0; kt < nkt; ++kt) {
        const int k0 = kt * BKV;
#pragma unroll
        for (int i = 0; i < 4; ++i) {
            int idx = tid + i * 256;
            int row = idx >> 4;
            int c4  = (idx & 15) << 2;
            float4 v = *reinterpret_cast<const float4*>(
                &Kh[(size_t)(k0 + row) * D_ + c4]);
            Kt[c4 + 0][row] = v.x; Kt[c4 + 1][row] = v.y;
            Kt[c4 + 2][row] = v.z; Kt[c4 + 3][row] = v.w;
        }
        __syncthreads();

        float accs[4][4] = {};
        for (int d = 0; d < D_; ++d) {
            float4 a4 = *reinterpret_cast<const float4*>(&Qt[d][tr * 4]);
            float4 b4 = *reinterpret_cast<const float4*>(&Kt[d][tc * 4]);
            float av[4] = {a4.x, a4.y, a4.z, a4.w};
            float bv[4] = {b4.x, b4.y, b4.z, b4.w};
#pragma unroll
            for (int i = 0; i < 4; ++i)
#pragma unroll
                for (int j = 0; j < 4; ++j)
                    accs[i][j] = fmaf(av[i], bv[j], accs[i][j]);
        }
        const bool diag = (kt == qt);
#pragma unroll
        for (int i = 0; i < 4; ++i) {
            float4 o;
            float* op = &o.x;
#pragma unroll
            for (int j = 0; j < 4; ++j) {
                float s = accs[i][j] * 0.125f;
                if (diag && (tc * 4 + j) > (tr * 4 + i)) s = -1e30f;
                op[j] = s;
            }
            *reinterpret_cast<float4*>(&sc[tr * 4 + i][tc * 4]) = o;
        }
        __syncthreads();

        {   // online row reduce: 4 threads per row
            int r  = tid >> 2;
            int c0 = (tid & 3) << 4;
            float mx = -INFINITY;
#pragma unroll
            for (int c = 0; c < 16; ++c) mx = fmaxf(mx, sc[r][c0 + c]);
            mx = fmaxf(mx, __shfl_xor(mx, 1));
            mx = fmaxf(mx, __shfl_xor(mx, 2));
            float mold = mrow[r];
            float mnew = fmaxf(mold, mx);
            float sum = 0.f;
#pragma unroll
            for (int c = 0; c < 16; ++c) sum += __expf(sc[r][c0 + c] - mnew);
            sum += __shfl_xor(sum, 1);
            sum += __shfl_xor(sum, 2);
            if ((tid & 3) == 0) {
                lrow[r] = lrow[r] * __expf(mold - mnew) + sum;
                mrow[r] = mnew;
            }
        }
        __syncthreads();
    }

    if (tid < BQ) lrow[tid] = 1.0f / lrow[tid];   // invert denom
    __syncthreads();

    // ---------------- pass 2: weights + PV ----------------
    const int pq = tid >> 2;          // PV mapping: 4 threads per q row
    const int pd = (tid & 3) << 4;    // 16 d-columns each
    float4 acc0 = {0,0,0,0}, acc1 = {0,0,0,0}, acc2 = {0,0,0,0}, acc3 = {0,0,0,0};

    for (int kt = 0; kt < nkt; ++kt) {
        const int k0 = kt * BKV;
#pragma unroll
        for (int i = 0; i < 4; ++i) {
            int idx = tid + i * 256;
            int row = idx >> 4;
            int c4  = (idx & 15) << 2;
            float4 kv = *reinterpret_cast<const float4*>(
                &Kh[(size_t)(k0 + row) * D_ + c4]);
            Kt[c4 + 0][row] = kv.x; Kt[c4 + 1][row] = kv.y;
            Kt[c4 + 2][row] = kv.z; Kt[c4 + 3][row] = kv.w;
            float4 vv = *reinterpret_cast<const float4*>(
                &Vh[(size_t)(k0 + row) * D_ + c4]);
            *reinterpret_cast<float4*>(&Vs[row][c4]) = vv;
        }
        __syncthreads();

        float accs[4][4] = {};
        for (int d = 0; d < D_; ++d) {
            float4 a4 = *reinterpret_cast<const float4*>(&Qt[d][tr * 4]);
            float4 b4 = *reinterpret_cast<const float4*>(&Kt[d][tc * 4]);
            float av[4] = {a4.x, a4.y, a4.z, a4.w};
            float bv[4] = {b4.x, b4.y, b4.z, b4.w};
#pragma unroll
            for (int i = 0; i < 4; ++i)
#pragma unroll
                for (int j = 0; j < 4; ++j)
                    accs[i][j] = fmaf(av[i], bv[j], accs[i][j]);
        }
        const bool diag = (kt == qt);
#pragma unroll
        for (int i = 0; i < 4; ++i) {
            const int r = tr * 4 + i;
            const float m = mrow[r], linv = lrow[r];
            float4 o;
            float* op = &o.x;
#pragma unroll
            for (int j = 0; j < 4; ++j) {
                float s = accs[i][j] * 0.125f;
                op[j] = (diag && (tc * 4 + j) > r) ? 0.f
                                                   : __expf(s - m) * linv;
            }
            *reinterpret_cast<float4*>(&sc[r][tc * 4]) = o;
            *reinterpret_cast<float4*>(&wrow[(size_t)r * S_ + k0 + tc * 4]) = o;
        }
        __syncthreads();

        // PV: acc[q][d] += w[q][k] * V[k][d]
        for (int kk = 0; kk < BKV; ++kk) {
            float wv = sc[pq][kk];
            float4 v0 = *reinterpret_cast<const float4*>(&Vs[kk][pd + 0]);
            float4 v1 = *reinterpret_cast<const float4*>(&Vs[kk][pd + 4]);
            float4 v2 = *reinterpret_cast<const float4*>(&Vs[kk][pd + 8]);
            float4 v3 = *reinterpret_cast<const float4*>(&Vs[kk][pd + 12]);
            acc0.x = fmaf(wv, v0.x, acc0.x); acc0.y = fmaf(wv, v0.y, acc0.y);
            acc0.z = fmaf(wv, v0.z, acc0.z); acc0.w = fmaf(wv, v0.w, acc0.w);
            acc1.x = fmaf(wv, v1.x, acc1.x); acc1.y = fmaf(wv, v1.y, acc1.y);
            acc1.z = fmaf(wv, v1.z, acc1.z); acc1.w = fmaf(wv, v1.w, acc1.w);
            acc2.x = fmaf(wv, v2.x, acc2.x); acc2.y = fmaf(wv, v2.y, acc2.y);
            acc2.z = fmaf(wv, v2.z, acc2.z); acc2.w = fmaf(wv, v2.w, acc2.w);
            acc3.x = fmaf(wv, v3.x, acc3.x); acc3.y = fmaf(wv, v3.y, acc3.y);
            acc3.z = fmaf(wv, v3.z, acc3.z); acc3.w = fmaf(wv, v3.w, acc3.w);
        }
        __syncthreads();
    }

    // zero-fill strictly-upper k-tiles of the weights output
    float4 z = {0.f, 0.f, 0.f, 0.f};
    for (int kt = nkt; kt < S_ / BKV; ++kt) {
        const int k0 = kt * BKV;
#pragma unroll
        for (int i = 0; i < 4; ++i) {
            int idx = tid + i * 256;
            int row = idx >> 4;
            int c4  = (idx & 15) << 2;
            *reinterpret_cast<float4*>(&wrow[(size_t)row * S_ + k0 + c4]) = z;
        }
    }

    // ctx write: merged-head [B,S,E]
    float* cp = &ctx[((size_t)b * S_ + q0 + pq) * E_ + h * D_ + pd];
    *reinterpret_cast<float4*>(&cp[0])  = acc0;
    *reinterpret_cast<float4*>(&cp[4])  = acc1;
    *reinterpret_cast<float4*>(&cp[8])  = acc2;
    *reinterpret_cast<float4*>(&cp[12]) = acc3;
}

// ---------------------------------------------------------------------------
// Kernel 3: out = ctx @ w_out + b_out    (M=8192, N=1024, K=1024)
// ---------------------------------------------------------------------------
__global__ __launch_bounds__(256)
void proj_kernel(const float* __restrict__ ctx, const float* __restrict__ w,
                 const float* __restrict__ bias, float* __restrict__ out) {
    constexpr int BM = 64, BN = 64, BK = 16;
    __shared__ float As[BK][BM + 4];
    __shared__ float Bs[BK][BN + 4];
    const int bn = blockIdx.x * BN;
    const int bm = blockIdx.y * BM;
    const int tid = threadIdx.x;
    const int tr = tid >> 4, tc = tid & 15;

    float acc[4][4] = {};
    for (int k0 = 0; k0 < E_; k0 += BK) {
        {
            int m  = tid >> 2;
            int k4 = (tid & 3) << 2;
            float4 a = *reinterpret_cast<const float4*>(
                &ctx[(size_t)(bm + m) * E_ + k0 + k4]);
            As[k4 + 0][m] = a.x; As[k4 + 1][m] = a.y;
            As[k4 + 2][m] = a.z; As[k4 + 3][m] = a.w;
        }
        {
            int k  = tid >> 4;
            int n4 = (tid & 15) << 2;
            float4 b = *reinterpret_cast<const float4*>(
                &w[(size_t)(k0 + k) * E_ + bn + n4]);
            *reinterpret_cast<float4*>(&Bs[k][n4]) = b;
        }
        __syncthreads();
#pragma unroll
        for (int k = 0; k < BK; ++k) {
            float4 a4 = *reinterpret_cast<const float4*>(&As[k][tr * 4]);
            float4 b4 = *reinterpret_cast<const float4*>(&Bs[k][tc * 4]);
            float av[4] = {a4.x, a4.y, a4.z, a4.w};
            float bv[4] = {b4.x, b4.y, b4.z, b4.w};
#pragma unroll
            for (int i = 0; i < 4; ++i)
#pragma unroll
                for (int j = 0; j < 4; ++j)
                    acc[i][j] = fmaf(av[i], bv[j], acc[i][j]);
        }
        __syncthreads();
    }

    float4 bias4 = *reinterpret_cast<const float4*>(&bias[bn + tc * 4]);
#pragma unroll
    for (int i = 0; i < 4; ++i) {
        float4 o;
        o.x = acc[i][0] + bias4.x; o.y = acc[i][1] + bias4.y;
        o.z = acc[i][2] + bias4.z; o.w = acc[i][3] + bias4.w;
        *reinterpret_cast<float4*>(
            &out[(size_t)(bm + tr * 4 + i) * E_ + bn + tc * 4]) = o;
    }
}

// ---------------------------------------------------------------------------
extern "C" void kernel_launch(void* const* d_in, const int* in_sizes, int n_in,
                              void* d_out, int out_size, void* d_ws,
                              size_t ws_size, hipStream_t stream) {
    (void)in_sizes; (void)n_in; (void)out_size; (void)ws_size;
    const float* x     = (const float*)d_in[0];
    const float* w_qkv = (const float*)d_in[1];
    const float* b_qkv = (const float*)d_in[2];
    const float* w_out = (const float*)d_in[3];
    const float* b_out = (const float*)d_in[4];

    float* out = (float*)d_out;                       // [B,S,E]
    float* wts = out + (size_t)M_ * E_;               // [B,H,S,S]

    const size_t per = (size_t)B_ * H_ * S_ * D_;     // 8,388,608 floats
    float* Qb  = (float*)d_ws;
    float* Kb  = Qb + per;
    float* Vb  = Kb + per;
    float* ctx = Vb + per;                            // [B,S,E] merged heads

    qkv_kernel<<<dim3(N3 / 64, M_ / 64), 256, 0, stream>>>(
        x, w_qkv, b_qkv, Qb, Kb, Vb);
    attn_kernel<<<dim3(S_ / 64, H_, B_), 256, 0, stream>>>(
        Qb, Kb, Vb, wts, ctx);
    proj_kernel<<<dim3(E_ / 64, M_ / 64), 256, 0, stream>>>(
        ctx, w_out, b_out, out);
}

// Round 7
// 2339.876 us; speedup vs baseline: 1.4825x; 1.4825x over previous
//
#include <hip/hip_runtime.h>
#include <math.h>

typedef __attribute__((ext_vector_type(4))) float  f32x4;
typedef __attribute__((ext_vector_type(8))) __bf16 bf16x8;
typedef __attribute__((ext_vector_type(4))) __bf16 bf16x4;

constexpr int B_ = 4, S_ = 2048, E_ = 1024, H_ = 16, D_ = 64;
constexpr int M_ = B_ * S_;   // 8192 rows of x
constexpr int N3 = 3 * E_;    // 3072 qkv cols

__device__ __forceinline__ f32x4 mfma16(bf16x8 a, bf16x8 b, f32x4 c) {
    return __builtin_amdgcn_mfma_f32_16x16x32_bf16(a, b, c, 0, 0, 0);
}
// split fp32 into bf16 hi + bf16 lo (x ≈ hi + lo), RNE both times.
// NOTE: callers pass scalar locals (refs can't bind to vector elements).
__device__ __forceinline__ void split2(float x, __bf16& h, __bf16& l) {
    h = (__bf16)x;
    l = (__bf16)(x - (float)h);
}

// ---------------------------------------------------------------------------
// Kernel 1: qkv = x @ w_qkv + b_qkv, scatter to Q/K/V [B,H,S,D]. (unchanged)
// ---------------------------------------------------------------------------
__global__ __launch_bounds__(256)
void qkv_kernel(const float* __restrict__ x, const float* __restrict__ w,
                const float* __restrict__ bias,
                float* __restrict__ Qb, float* __restrict__ Kb,
                float* __restrict__ Vb) {
    constexpr int BK = 16;
    __shared__ float As[BK][64 + 4];
    __shared__ float Bs[BK][64 + 4];
    const int bn = blockIdx.x * 64;
    const int bm = blockIdx.y * 64;
    const int tid = threadIdx.x;
    const int tr = tid >> 4, tc = tid & 15;

    float acc[4][4] = {};
    for (int k0 = 0; k0 < E_; k0 += BK) {
        {
            int m  = tid >> 2;
            int k4 = (tid & 3) << 2;
            float4 a = *reinterpret_cast<const float4*>(
                &x[(size_t)(bm + m) * E_ + k0 + k4]);
            As[k4 + 0][m] = a.x; As[k4 + 1][m] = a.y;
            As[k4 + 2][m] = a.z; As[k4 + 3][m] = a.w;
        }
        {
            int k  = tid >> 4;
            int n4 = (tid & 15) << 2;
            float4 b = *reinterpret_cast<const float4*>(
                &w[(size_t)(k0 + k) * N3 + bn + n4]);
            *reinterpret_cast<float4*>(&Bs[k][n4]) = b;
        }
        __syncthreads();
#pragma unroll
        for (int k = 0; k < BK; ++k) {
            float4 a4 = *reinterpret_cast<const float4*>(&As[k][tr * 4]);
            float4 b4 = *reinterpret_cast<const float4*>(&Bs[k][tc * 4]);
            float av[4] = {a4.x, a4.y, a4.z, a4.w};
            float bv[4] = {b4.x, b4.y, b4.z, b4.w};
#pragma unroll
            for (int i = 0; i < 4; ++i)
#pragma unroll
                for (int j = 0; j < 4; ++j)
                    acc[i][j] = fmaf(av[i], bv[j], acc[i][j]);
        }
        __syncthreads();
    }

    const int t = bn / E_;
    const int h = (bn % E_) >> 6;
    float* dst = (t == 0) ? Qb : (t == 1) ? Kb : Vb;
    const int b  = bm / S_;
    const int s0 = bm % S_;
    const size_t base = ((size_t)(b * H_ + h) * S_ + s0) * D_;
    float4 bias4 = *reinterpret_cast<const float4*>(&bias[bn + tc * 4]);
#pragma unroll
    for (int i = 0; i < 4; ++i) {
        int r = tr * 4 + i;
        float4 o;
        o.x = acc[i][0] + bias4.x; o.y = acc[i][1] + bias4.y;
        o.z = acc[i][2] + bias4.z; o.w = acc[i][3] + bias4.w;
        *reinterpret_cast<float4*>(&dst[base + (size_t)r * D_ + tc * 4]) = o;
    }
}

// ---------------------------------------------------------------------------
// LDS staging helpers for attention (MFMA version).
// K tile: [64 k][64 d] fp32 -> hi/lo bf16, row-major, 16B-slot XOR swizzle
//   (slot' = slot ^ (row&7)) to kill the stride-128B bank conflict (G4).
// V tile: packed in B-fragment order: elem (k,d) at idx (kg*64+d)*8+kc,
//   kg=k>>3, kc=k&7 -> B-frag read is one contiguous 16B per lane.
// ---------------------------------------------------------------------------
__device__ __forceinline__ void stage_K(const float* __restrict__ src,
                                        __bf16* Khi, __bf16* Klo, int tid) {
    const int r0   = tid >> 4;          // 16 rows per sweep
    const int c4   = (tid & 15) * 4;    // 4 cols per thread
    const int slot = (tid & 15) >> 1;   // 16B slot (8 bf16) index 0..7
    const int half = (tid & 15) & 1;    // which 8B half of the slot
#pragma unroll
    for (int i = 0; i < 4; ++i) {
        const int row = r0 + 16 * i;
        float4 v = *reinterpret_cast<const float4*>(&src[row * 64 + c4]);
        const int slotp = slot ^ (row & 7);
        const int idx = row * 64 + slotp * 8 + half * 4;
        bf16x4 hv, lv;
        __bf16 h0, l0;
        split2(v.x, h0, l0); hv[0] = h0; lv[0] = l0;
        split2(v.y, h0, l0); hv[1] = h0; lv[1] = l0;
        split2(v.z, h0, l0); hv[2] = h0; lv[2] = l0;
        split2(v.w, h0, l0); hv[3] = h0; lv[3] = l0;
        *reinterpret_cast<bf16x4*>(Khi + idx) = hv;
        *reinterpret_cast<bf16x4*>(Klo + idx) = lv;
    }
}

__device__ __forceinline__ void stage_V(const float* __restrict__ src,
                                        __bf16* Vhi, __bf16* Vlo, int tid) {
    const int kb  = tid >> 4;           // 4 k-rows per thread
    const int dq  = (tid & 15) * 4;     // 4 d-cols per thread
    const int kg  = kb >> 1;
    const int kc0 = (kb & 1) * 4;
    float rv[16];
#pragma unroll
    for (int i = 0; i < 4; ++i) {
        float4 t = *reinterpret_cast<const float4*>(&src[(kb * 4 + i) * 64 + dq]);
        rv[i * 4 + 0] = t.x; rv[i * 4 + 1] = t.y;
        rv[i * 4 + 2] = t.z; rv[i * 4 + 3] = t.w;
    }
#pragma unroll
    for (int di = 0; di < 4; ++di) {
        bf16x4 hv, lv;
        __bf16 h0, l0;
        split2(rv[0 * 4 + di], h0, l0); hv[0] = h0; lv[0] = l0;
        split2(rv[1 * 4 + di], h0, l0); hv[1] = h0; lv[1] = l0;
        split2(rv[2 * 4 + di], h0, l0); hv[2] = h0; lv[2] = l0;
        split2(rv[3 * 4 + di], h0, l0); hv[3] = h0; lv[3] = l0;
        const int idx = (kg * 64 + (dq + di)) * 8 + kc0;
        *reinterpret_cast<bf16x4*>(Vhi + idx) = hv;
        *reinterpret_cast<bf16x4*>(Vlo + idx) = lv;
    }
}

// QK^T for one 16(q)x64(k) strip: 4 subtiles x 2 K-chunks x 3 split-MFMAs.
// lg[s][r] = scaled, causal-masked logits. D-layout: row=lq*4+r, col=lr.
__device__ __forceinline__ void qk_tile(const __bf16* Khi, const __bf16* Klo,
                                        const bf16x8* qh, const bf16x8* ql,
                                        int lr, int lq, bool diag,
                                        int qrow0, int k0, f32x4 lg[4]) {
#pragma unroll
    for (int s = 0; s < 4; ++s) {
        f32x4 a = {0.f, 0.f, 0.f, 0.f};
        const int row = 16 * s + lr;
#pragma unroll
        for (int c = 0; c < 2; ++c) {
            const int slotp = (4 * c + lq) ^ (row & 7);
            bf16x8 kh = *reinterpret_cast<const bf16x8*>(Khi + row * 64 + slotp * 8);
            bf16x8 kl = *reinterpret_cast<const bf16x8*>(Klo + row * 64 + slotp * 8);
            a = mfma16(qh[c], kh, a);
            a = mfma16(ql[c], kh, a);
            a = mfma16(qh[c], kl, a);
        }
#pragma unroll
        for (int r = 0; r < 4; ++r) {
            float v = a[r] * 0.125f;
            if (diag && (k0 + 16 * s + lr) > (qrow0 + lq * 4 + r)) v = -1e30f;
            lg[s][r] = v;
        }
    }
}

// ---------------------------------------------------------------------------
// Kernel 2: causal attention, split-bf16 MFMA. Grid (qt, h, b), 256 thr.
// Wave w owns q-rows [q0+16w, q0+16w+16). Two passes over k-tiles:
//   pass 1: online row max m / denom l (registers only)
//   pass 2: recompute logits, weights -> sc LDS -> global (float4) + PV MFMA
// ---------------------------------------------------------------------------
__global__ __launch_bounds__(256, 3)
void attn_kernel(const float* __restrict__ Qg, const float* __restrict__ Kg,
                 const float* __restrict__ Vg, float* __restrict__ wts,
                 float* __restrict__ ctx) {
    __shared__ __align__(16) __bf16 Khi[4096];
    __shared__ __align__(16) __bf16 Klo[4096];
    __shared__ __align__(16) __bf16 Vhi[4096];
    __shared__ __align__(16) __bf16 Vlo[4096];
    __shared__ float sc[64][68];

    const int qt = blockIdx.x, h = blockIdx.y, b = blockIdx.z;
    const int q0 = qt * 64;
    const int tid = threadIdx.x;
    const int lane = tid & 63;
    const int w  = tid >> 6;     // wave id 0..3
    const int lr = lane & 15;    // lane-low: col in D-layout / row in A-frag
    const int lq = lane >> 4;    // quarter id

    const size_t headbase = (size_t)(b * H_ + h) * S_ * D_;
    const float* Qp = Qg + headbase;
    const float* Kp = Kg + headbase;
    const float* Vp = Vg + headbase;
    float* wrow = wts + ((size_t)(b * H_ + h) * S_ + q0) * S_;

    // ---- Q fragments: lane holds Q[q0+16w+lr][lq*8 + 32c + j] ----
    bf16x8 qh[2], ql[2];
    {
        const int qrow = q0 + 16 * w + lr;
#pragma unroll
        for (int c = 0; c < 2; ++c) {
            const float* qp = &Qp[(size_t)qrow * D_ + c * 32 + lq * 8];
            float4 a  = *reinterpret_cast<const float4*>(qp);
            float4 bq = *reinterpret_cast<const float4*>(qp + 4);
            float v8[8] = {a.x, a.y, a.z, a.w, bq.x, bq.y, bq.z, bq.w};
#pragma unroll
            for (int j = 0; j < 8; ++j) {
                __bf16 h0, l0;
                split2(v8[j], h0, l0);
                qh[c][j] = h0; ql[c][j] = l0;
            }
        }
    }

    const int nkt = qt + 1;
    const int qrow0 = q0 + 16 * w;

    float m_run[4], l_run[4];
#pragma unroll
    for (int r = 0; r < 4; ++r) { m_run[r] = -INFINITY; l_run[r] = 0.f; }

    // ---------------- pass 1: row max + denom ----------------
    for (int kt = 0; kt < nkt; ++kt) {
        __syncthreads();
        stage_K(&Kp[(size_t)kt * 4096], Khi, Klo, tid);
        __syncthreads();
        f32x4 lg[4];
        qk_tile(Khi, Klo, qh, ql, lr, lq, kt == qt, qrow0, kt * 64, lg);
#pragma unroll
        for (int r = 0; r < 4; ++r) {
            float mx = fmaxf(fmaxf(lg[0][r], lg[1][r]), fmaxf(lg[2][r], lg[3][r]));
            mx = fmaxf(mx, __shfl_xor(mx, 1));
            mx = fmaxf(mx, __shfl_xor(mx, 2));
            mx = fmaxf(mx, __shfl_xor(mx, 4));
            mx = fmaxf(mx, __shfl_xor(mx, 8));
            const float mnew = fmaxf(m_run[r], mx);
            float ps = __expf(lg[0][r] - mnew) + __expf(lg[1][r] - mnew) +
                       __expf(lg[2][r] - mnew) + __expf(lg[3][r] - mnew);
            ps += __shfl_xor(ps, 1);
            ps += __shfl_xor(ps, 2);
            ps += __shfl_xor(ps, 4);
            ps += __shfl_xor(ps, 8);
            l_run[r] = l_run[r] * __expf(m_run[r] - mnew) + ps;
            m_run[r] = mnew;
        }
    }

    float linv[4];
#pragma unroll
    for (int r = 0; r < 4; ++r) linv[r] = 1.0f / l_run[r];

    // ---------------- pass 2: weights + PV ----------------
    f32x4 acc[4];
#pragma unroll
    for (int s = 0; s < 4; ++s) acc[s] = (f32x4){0.f, 0.f, 0.f, 0.f};

    for (int kt = 0; kt < nkt; ++kt) {
        __syncthreads();
        stage_K(&Kp[(size_t)kt * 4096], Khi, Klo, tid);
        stage_V(&Vp[(size_t)kt * 4096], Vhi, Vlo, tid);
        __syncthreads();

        f32x4 lg[4];
        qk_tile(Khi, Klo, qh, ql, lr, lq, kt == qt, qrow0, kt * 64, lg);
        // normalized weights -> sc  (masked: exp(-1e30 - m) underflows to 0)
#pragma unroll
        for (int s = 0; s < 4; ++s)
#pragma unroll
            for (int r = 0; r < 4; ++r)
                sc[16 * w + lq * 4 + r][16 * s + lr] =
                    __expf(lg[s][r] - m_run[r]) * linv[r];
        __syncthreads();

        // cooperative coalesced float4 store of the weight tile
        {
            const int c4 = (tid & 15) * 4;
            const int r0 = tid >> 4;
#pragma unroll
            for (int i = 0; i < 4; ++i) {
                const int row = r0 + 16 * i;
                float4 w4 = *reinterpret_cast<const float4*>(&sc[row][c4]);
                *reinterpret_cast<float4*>(
                    &wrow[(size_t)row * S_ + kt * 64 + c4]) = w4;
            }
        }

        // P A-fragments from sc: lane holds P[16w+lr][lq*8 + 32c + j]
        bf16x8 pah[2], pal[2];
#pragma unroll
        for (int c = 0; c < 2; ++c) {
            const float* pr = &sc[16 * w + lr][lq * 8 + 32 * c];
            float4 p0 = *reinterpret_cast<const float4*>(pr);
            float4 p1 = *reinterpret_cast<const float4*>(pr + 4);
            float v8[8] = {p0.x, p0.y, p0.z, p0.w, p1.x, p1.y, p1.z, p1.w};
#pragma unroll
            for (int j = 0; j < 8; ++j) {
                __bf16 h0, l0;
                split2(v8[j], h0, l0);
                pah[c][j] = h0; pal[c][j] = l0;
            }
        }

        // PV: acc[s2] over d-subtiles; B-frag = packed V
#pragma unroll
        for (int s2 = 0; s2 < 4; ++s2) {
#pragma unroll
            for (int c = 0; c < 2; ++c) {
                const int kg = 4 * c + lq;
                const int d  = 16 * s2 + lr;
                bf16x8 vh = *reinterpret_cast<const bf16x8*>(Vhi + (kg * 64 + d) * 8);
                bf16x8 vl = *reinterpret_cast<const bf16x8*>(Vlo + (kg * 64 + d) * 8);
                acc[s2] = mfma16(pah[c], vh, acc[s2]);
                acc[s2] = mfma16(pah[c], vl, acc[s2]);
                acc[s2] = mfma16(pal[c], vh, acc[s2]);
            }
        }
    }

    // zero-fill strictly-upper k-tiles of the weights output
    {
        float4 z = {0.f, 0.f, 0.f, 0.f};
        const int c4 = (tid & 15) * 4;
        const int r0 = tid >> 4;
        for (int kt = nkt; kt < S_ / 64; ++kt) {
#pragma unroll
            for (int i = 0; i < 4; ++i) {
                const int row = r0 + 16 * i;
                *reinterpret_cast<float4*>(
                    &wrow[(size_t)row * S_ + kt * 64 + c4]) = z;
            }
        }
    }

    // ctx write, merged-head [B,S,E]: row = q, col = h*64 + 16*s2 + lr
#pragma unroll
    for (int s2 = 0; s2 < 4; ++s2)
#pragma unroll
        for (int r = 0; r < 4; ++r)
            ctx[((size_t)b * S_ + qrow0 + lq * 4 + r) * E_ + h * 64 + 16 * s2 + lr] =
                acc[s2][r];
}

// ---------------------------------------------------------------------------
// Kernel 3: out = ctx @ w_out + b_out. (unchanged)
// ---------------------------------------------------------------------------
__global__ __launch_bounds__(256)
void proj_kernel(const float* __restrict__ ctx, const float* __restrict__ w,
                 const float* __restrict__ bias, float* __restrict__ out) {
    constexpr int BK = 16;
    __shared__ float As[BK][64 + 4];
    __shared__ float Bs[BK][64 + 4];
    const int bn = blockIdx.x * 64;
    const int bm = blockIdx.y * 64;
    const int tid = threadIdx.x;
    const int tr = tid >> 4, tc = tid & 15;

    float acc[4][4] = {};
    for (int k0 = 0; k0 < E_; k0 += BK) {
        {
            int m  = tid >> 2;
            int k4 = (tid & 3) << 2;
            float4 a = *reinterpret_cast<const float4*>(
                &ctx[(size_t)(bm + m) * E_ + k0 + k4]);
            As[k4 + 0][m] = a.x; As[k4 + 1][m] = a.y;
            As[k4 + 2][m] = a.z; As[k4 + 3][m] = a.w;
        }
        {
            int k  = tid >> 4;
            int n4 = (tid & 15) << 2;
            float4 b = *reinterpret_cast<const float4*>(
                &w[(size_t)(k0 + k) * E_ + bn + n4]);
            *reinterpret_cast<float4*>(&Bs[k][n4]) = b;
        }
        __syncthreads();
#pragma unroll
        for (int k = 0; k < BK; ++k) {
            float4 a4 = *reinterpret_cast<const float4*>(&As[k][tr * 4]);
            float4 b4 = *reinterpret_cast<const float4*>(&Bs[k][tc * 4]);
            float av[4] = {a4.x, a4.y, a4.z, a4.w};
            float bv[4] = {b4.x, b4.y, b4.z, b4.w};
#pragma unroll
            for (int i = 0; i < 4; ++i)
#pragma unroll
                for (int j = 0; j < 4; ++j)
                    acc[i][j] = fmaf(av[i], bv[j], acc[i][j]);
        }
        __syncthreads();
    }

    float4 bias4 = *reinterpret_cast<const float4*>(&bias[bn + tc * 4]);
#pragma unroll
    for (int i = 0; i < 4; ++i) {
        float4 o;
        o.x = acc[i][0] + bias4.x; o.y = acc[i][1] + bias4.y;
        o.z = acc[i][2] + bias4.z; o.w = acc[i][3] + bias4.w;
        *reinterpret_cast<float4*>(
            &out[(size_t)(bm + tr * 4 + i) * E_ + bn + tc * 4]) = o;
    }
}

// ---------------------------------------------------------------------------
extern "C" void kernel_launch(void* const* d_in, const int* in_sizes, int n_in,
                              void* d_out, int out_size, void* d_ws,
                              size_t ws_size, hipStream_t stream) {
    (void)in_sizes; (void)n_in; (void)out_size; (void)ws_size;
    const float* x     = (const float*)d_in[0];
    const float* w_qkv = (const float*)d_in[1];
    const float* b_qkv = (const float*)d_in[2];
    const float* w_out = (const float*)d_in[3];
    const float* b_out = (const float*)d_in[4];

    float* out = (float*)d_out;                       // [B,S,E]
    float* wts = out + (size_t)M_ * E_;               // [B,H,S,S]

    const size_t per = (size_t)B_ * H_ * S_ * D_;     // 8,388,608 floats
    float* Qb  = (float*)d_ws;
    float* Kb  = Qb + per;
    float* Vb  = Kb + per;
    float* ctx = Vb + per;                            // [B,S,E] merged heads

    qkv_kernel<<<dim3(N3 / 64, M_ / 64), 256, 0, stream>>>(
        x, w_qkv, b_qkv, Qb, Kb, Vb);
    attn_kernel<<<dim3(S_ / 64, H_, B_), 256, 0, stream>>>(
        Qb, Kb, Vb, wts, ctx);
    proj_kernel<<<dim3(E_ / 64, M_ / 64), 256, 0, stream>>>(
        ctx, w_out, b_out, out);
}

// Round 9
// 1729.718 us; speedup vs baseline: 2.0055x; 1.3527x over previous
//
#include <hip/hip_runtime.h>
#include <math.h>

typedef __attribute__((ext_vector_type(4))) float  f32x4;
typedef __attribute__((ext_vector_type(8))) __bf16 bf16x8;
typedef __attribute__((ext_vector_type(4))) __bf16 bf16x4;

constexpr int B_ = 4, S_ = 2048, E_ = 1024, H_ = 16, D_ = 64;
constexpr int M_ = B_ * S_;   // 8192 rows of x
constexpr int N3 = 3 * E_;    // 3072 qkv cols

__device__ __forceinline__ f32x4 mfma16(bf16x8 a, bf16x8 b, f32x4 c) {
    return __builtin_amdgcn_mfma_f32_16x16x32_bf16(a, b, c, 0, 0, 0);
}
// split fp32 into bf16 hi + bf16 lo (x ≈ hi + lo), RNE both times.
// NOTE: callers pass scalar locals (refs can't bind to vector elements).
__device__ __forceinline__ void split2(float x, __bf16& h, __bf16& l) {
    h = (__bf16)x;
    l = (__bf16)(x - (float)h);
}

// ===========================================================================
// Split-bf16 MFMA GEMM core (HW-verified fragment layouts from attn_kernel):
//   A-frag: lane(lr,lq) holds A[row=lr][k=lq*8+j]   (16x32 tile)
//   B-frag: lane(lr,lq) holds B[k=lq*8+j][col=lr]   (32x16 tile)
//   D:      row = lq*4+r, col = lr                  (16x16 tile)
// Block: 128x128 C-tile, BK=32, 256 thr = 4 waves (2x2), wave does 64x64.
// LDS: fragment-order packed hi/lo for A and B; slot s=(blk*4+lq)*16+lr
// holds 8 bf16 at s*8 -> 16B per lane, linear across the wave (conflict-free
// on ds_write_b128 and ds_read_b128 alike).
// Staging reads global per-fragment: A = 2x contiguous float4 per slot;
// B = 8x stride-ldb scalars per slot (W is L2/L3-resident: 12.6 MB).
// 3 split products per fragment: AhBh + AlBh + AhBl (~2^-17 rel err).
// ===========================================================================
__device__ __forceinline__ void gemm_tile_core(
    const float* __restrict__ A, int lda,    // &A[bm][0]
    const float* __restrict__ Bm, int ldb,   // &B[0][bn]
    int K,
    __bf16* Ahi, __bf16* Alo, __bf16* Bhi, __bf16* Blo,
    f32x4 acc[4][4])
{
    const int tid  = threadIdx.x;
    const int lane = tid & 63;
    const int w    = tid >> 6;
    const int lr   = lane & 15;
    const int lq   = lane >> 4;
    const int wm   = w >> 1, wn = w & 1;

    for (int k0 = 0; k0 < K; k0 += 32) {
        __syncthreads();   // protect prior step's LDS reads
        // ---- stage A: 2 fragment slots per thread ----
#pragma unroll
        for (int i = 0; i < 2; ++i) {
            const int slot = tid + 256 * i;        // (mi*4+lq2)*16+lr2
            const int lr2 = slot & 15;
            const int lq2 = (slot >> 4) & 3;
            const int mi  = slot >> 6;             // 0..7
            const float* ap = A + (size_t)(mi * 16 + lr2) * lda + k0 + lq2 * 8;
            float4 a0 = *reinterpret_cast<const float4*>(ap);
            float4 a1 = *reinterpret_cast<const float4*>(ap + 4);
            float v8[8] = {a0.x, a0.y, a0.z, a0.w, a1.x, a1.y, a1.z, a1.w};
            bf16x8 hv, lv;
#pragma unroll
            for (int j = 0; j < 8; ++j) {
                __bf16 h0, l0;
                split2(v8[j], h0, l0);
                hv[j] = h0; lv[j] = l0;
            }
            *reinterpret_cast<bf16x8*>(Ahi + slot * 8) = hv;
            *reinterpret_cast<bf16x8*>(Alo + slot * 8) = lv;
        }
        // ---- stage B: 2 fragment slots per thread ----
#pragma unroll
        for (int i = 0; i < 2; ++i) {
            const int slot = tid + 256 * i;        // (ni*4+lq2)*16+lr2
            const int lr2 = slot & 15;
            const int lq2 = (slot >> 4) & 3;
            const int ni  = slot >> 6;             // 0..7
            const float* bp = Bm + (size_t)(k0 + lq2 * 8) * ldb + ni * 16 + lr2;
            bf16x8 hv, lv;
#pragma unroll
            for (int j = 0; j < 8; ++j) {
                __bf16 h0, l0;
                split2(bp[(size_t)j * ldb], h0, l0);
                hv[j] = h0; lv[j] = l0;
            }
            *reinterpret_cast<bf16x8*>(Bhi + slot * 8) = hv;
            *reinterpret_cast<bf16x8*>(Blo + slot * 8) = lv;
        }
        __syncthreads();

        // ---- compute: 16 fragments x 3 split-MFMAs ----
        bf16x8 ah[4], al[4], bh[4], bl[4];
#pragma unroll
        for (int t = 0; t < 4; ++t) {
            const int sa = ((wm * 4 + t) * 4 + lq) * 16 + lr;
            ah[t] = *reinterpret_cast<const bf16x8*>(Ahi + sa * 8);
            al[t] = *reinterpret_cast<const bf16x8*>(Alo + sa * 8);
            const int sb = ((wn * 4 + t) * 4 + lq) * 16 + lr;
            bh[t] = *reinterpret_cast<const bf16x8*>(Bhi + sb * 8);
            bl[t] = *reinterpret_cast<const bf16x8*>(Blo + sb * 8);
        }
#pragma unroll
        for (int mi = 0; mi < 4; ++mi)
#pragma unroll
            for (int ni = 0; ni < 4; ++ni) {
                acc[mi][ni] = mfma16(ah[mi], bh[ni], acc[mi][ni]);
                acc[mi][ni] = mfma16(al[mi], bh[ni], acc[mi][ni]);
                acc[mi][ni] = mfma16(ah[mi], bl[ni], acc[mi][ni]);
            }
    }
}

// ---------------------------------------------------------------------------
// Kernel 1: qkv = x @ w_qkv + b_qkv, scattered to Q/K/V [B,H,S,D]. MFMA.
// Grid (N3/128, M/128). Epilogue maps col -> (t, h, d), row -> (b, s).
// ---------------------------------------------------------------------------
__global__ __launch_bounds__(256, 2)
void qkv_kernel(const float* __restrict__ x, const float* __restrict__ wq,
                const float* __restrict__ bias,
                float* __restrict__ Qb, float* __restrict__ Kb,
                float* __restrict__ Vb) {
    __shared__ __align__(16) __bf16 Ahi[4096], Alo[4096];
    __shared__ __align__(16) __bf16 Bhi[4096], Blo[4096];

    const int bn = blockIdx.x * 128;
    const int bm = blockIdx.y * 128;
    const int tid  = threadIdx.x;
    const int lane = tid & 63;
    const int w    = tid >> 6;
    const int lr   = lane & 15;
    const int lq   = lane >> 4;
    const int wm   = w >> 1, wn = w & 1;

    f32x4 acc[4][4];
#pragma unroll
    for (int mi = 0; mi < 4; ++mi)
#pragma unroll
        for (int ni = 0; ni < 4; ++ni) acc[mi][ni] = (f32x4){0.f, 0.f, 0.f, 0.f};

    gemm_tile_core(x + (size_t)bm * E_, E_, wq + bn, N3, E_,
                   Ahi, Alo, Bhi, Blo, acc);

#pragma unroll
    for (int ni = 0; ni < 4; ++ni) {
        const int col  = bn + (wn * 4 + ni) * 16 + lr;
        const int t    = col >> 10;            // q/k/v
        const int hcol = col & 1023;
        const int h    = hcol >> 6;
        const int d    = hcol & 63;
        float* dst = (t == 0) ? Qb : (t == 1) ? Kb : Vb;
        const float bv = bias[col];
#pragma unroll
        for (int mi = 0; mi < 4; ++mi) {
#pragma unroll
            for (int r = 0; r < 4; ++r) {
                const int row = bm + (wm * 4 + mi) * 16 + lq * 4 + r;
                const int b = row >> 11;
                const int s = row & 2047;
                dst[(((size_t)(b * H_ + h)) * S_ + s) * D_ + d] =
                    acc[mi][ni][r] + bv;
            }
        }
    }
}

// ---------------------------------------------------------------------------
// LDS staging helpers for attention. (unchanged, HW-verified round 7)
// K tile: [64 k][64 d] fp32 -> hi/lo bf16, row-major, 16B-slot XOR swizzle
//   (slot' = slot ^ (row&7)) to kill the stride-128B bank conflict (G4).
// V tile: packed in B-fragment order: elem (k,d) at idx (kg*64+d)*8+kc,
//   kg=k>>3, kc=k&7 -> B-frag read is one contiguous 16B per lane.
// ---------------------------------------------------------------------------
__device__ __forceinline__ void stage_K(const float* __restrict__ src,
                                        __bf16* Khi, __bf16* Klo, int tid) {
    const int r0   = tid >> 4;          // 16 rows per sweep
    const int c4   = (tid & 15) * 4;    // 4 cols per thread
    const int slot = (tid & 15) >> 1;   // 16B slot (8 bf16) index 0..7
    const int half = (tid & 15) & 1;    // which 8B half of the slot
#pragma unroll
    for (int i = 0; i < 4; ++i) {
        const int row = r0 + 16 * i;
        float4 v = *reinterpret_cast<const float4*>(&src[row * 64 + c4]);
        const int slotp = slot ^ (row & 7);
        const int idx = row * 64 + slotp * 8 + half * 4;
        bf16x4 hv, lv;
        __bf16 h0, l0;
        split2(v.x, h0, l0); hv[0] = h0; lv[0] = l0;
        split2(v.y, h0, l0); hv[1] = h0; lv[1] = l0;
        split2(v.z, h0, l0); hv[2] = h0; lv[2] = l0;
        split2(v.w, h0, l0); hv[3] = h0; lv[3] = l0;
        *reinterpret_cast<bf16x4*>(Khi + idx) = hv;
        *reinterpret_cast<bf16x4*>(Klo + idx) = lv;
    }
}

__device__ __forceinline__ void stage_V(const float* __restrict__ src,
                                        __bf16* Vhi, __bf16* Vlo, int tid) {
    const int kb  = tid >> 4;           // 4 k-rows per thread
    const int dq  = (tid & 15) * 4;     // 4 d-cols per thread
    const int kg  = kb >> 1;
    const int kc0 = (kb & 1) * 4;
    float rv[16];
#pragma unroll
    for (int i = 0; i < 4; ++i) {
        float4 t = *reinterpret_cast<const float4*>(&src[(kb * 4 + i) * 64 + dq]);
        rv[i * 4 + 0] = t.x; rv[i * 4 + 1] = t.y;
        rv[i * 4 + 2] = t.z; rv[i * 4 + 3] = t.w;
    }
#pragma unroll
    for (int di = 0; di < 4; ++di) {
        bf16x4 hv, lv;
        __bf16 h0, l0;
        split2(rv[0 * 4 + di], h0, l0); hv[0] = h0; lv[0] = l0;
        split2(rv[1 * 4 + di], h0, l0); hv[1] = h0; lv[1] = l0;
        split2(rv[2 * 4 + di], h0, l0); hv[2] = h0; lv[2] = l0;
        split2(rv[3 * 4 + di], h0, l0); hv[3] = h0; lv[3] = l0;
        const int idx = (kg * 64 + (dq + di)) * 8 + kc0;
        *reinterpret_cast<bf16x4*>(Vhi + idx) = hv;
        *reinterpret_cast<bf16x4*>(Vlo + idx) = lv;
    }
}

// QK^T for one 16(q)x64(k) strip: 4 subtiles x 2 K-chunks x 3 split-MFMAs.
// lg[s][r] = scaled, causal-masked logits. D-layout: row=lq*4+r, col=lr.
__device__ __forceinline__ void qk_tile(const __bf16* Khi, const __bf16* Klo,
                                        const bf16x8* qh, const bf16x8* ql,
                                        int lr, int lq, bool diag,
                                        int qrow0, int k0, f32x4 lg[4]) {
#pragma unroll
    for (int s = 0; s < 4; ++s) {
        f32x4 a = {0.f, 0.f, 0.f, 0.f};
        const int row = 16 * s + lr;
#pragma unroll
        for (int c = 0; c < 2; ++c) {
            const int slotp = (4 * c + lq) ^ (row & 7);
            bf16x8 kh = *reinterpret_cast<const bf16x8*>(Khi + row * 64 + slotp * 8);
            bf16x8 kl = *reinterpret_cast<const bf16x8*>(Klo + row * 64 + slotp * 8);
            a = mfma16(qh[c], kh, a);
            a = mfma16(ql[c], kh, a);
            a = mfma16(qh[c], kl, a);
        }
#pragma unroll
        for (int r = 0; r < 4; ++r) {
            float v = a[r] * 0.125f;
            if (diag && (k0 + 16 * s + lr) > (qrow0 + lq * 4 + r)) v = -1e30f;
            lg[s][r] = v;
        }
    }
}

// ---------------------------------------------------------------------------
// Kernel 2: causal attention, split-bf16 MFMA. (unchanged, verified round 7)
// ---------------------------------------------------------------------------
__global__ __launch_bounds__(256, 3)
void attn_kernel(const float* __restrict__ Qg, const float* __restrict__ Kg,
                 const float* __restrict__ Vg, float* __restrict__ wts,
                 float* __restrict__ ctx) {
    __shared__ __align__(16) __bf16 Khi[4096];
    __shared__ __align__(16) __bf16 Klo[4096];
    __shared__ __align__(16) __bf16 Vhi[4096];
    __shared__ __align__(16) __bf16 Vlo[4096];
    __shared__ float sc[64][68];

    const int qt = blockIdx.x, h = blockIdx.y, b = blockIdx.z;
    const int q0 = qt * 64;
    const int tid = threadIdx.x;
    const int lane = tid & 63;
    const int w  = tid >> 6;     // wave id 0..3
    const int lr = lane & 15;    // lane-low: col in D-layout / row in A-frag
    const int lq = lane >> 4;    // quarter id

    const size_t headbase = (size_t)(b * H_ + h) * S_ * D_;
    const float* Qp = Qg + headbase;
    const float* Kp = Kg + headbase;
    const float* Vp = Vg + headbase;
    float* wrow = wts + ((size_t)(b * H_ + h) * S_ + q0) * S_;

    // ---- Q fragments: lane holds Q[q0+16w+lr][lq*8 + 32c + j] ----
    bf16x8 qh[2], ql[2];
    {
        const int qrow = q0 + 16 * w + lr;
#pragma unroll
        for (int c = 0; c < 2; ++c) {
            const float* qp = &Qp[(size_t)qrow * D_ + c * 32 + lq * 8];
            float4 a  = *reinterpret_cast<const float4*>(qp);
            float4 bq = *reinterpret_cast<const float4*>(qp + 4);
            float v8[8] = {a.x, a.y, a.z, a.w, bq.x, bq.y, bq.z, bq.w};
#pragma unroll
            for (int j = 0; j < 8; ++j) {
                __bf16 h0, l0;
                split2(v8[j], h0, l0);
                qh[c][j] = h0; ql[c][j] = l0;
            }
        }
    }

    const int nkt = qt + 1;
    const int qrow0 = q0 + 16 * w;

    float m_run[4], l_run[4];
#pragma unroll
    for (int r = 0; r < 4; ++r) { m_run[r] = -INFINITY; l_run[r] = 0.f; }

    // ---------------- pass 1: row max + denom ----------------
    for (int kt = 0; kt < nkt; ++kt) {
        __syncthreads();
        stage_K(&Kp[(size_t)kt * 4096], Khi, Klo, tid);
        __syncthreads();
        f32x4 lg[4];
        qk_tile(Khi, Klo, qh, ql, lr, lq, kt == qt, qrow0, kt * 64, lg);
#pragma unroll
        for (int r = 0; r < 4; ++r) {
            float mx = fmaxf(fmaxf(lg[0][r], lg[1][r]), fmaxf(lg[2][r], lg[3][r]));
            mx = fmaxf(mx, __shfl_xor(mx, 1));
            mx = fmaxf(mx, __shfl_xor(mx, 2));
            mx = fmaxf(mx, __shfl_xor(mx, 4));
            mx = fmaxf(mx, __shfl_xor(mx, 8));
            const float mnew = fmaxf(m_run[r], mx);
            float ps = __expf(lg[0][r] - mnew) + __expf(lg[1][r] - mnew) +
                       __expf(lg[2][r] - mnew) + __expf(lg[3][r] - mnew);
            ps += __shfl_xor(ps, 1);
            ps += __shfl_xor(ps, 2);
            ps += __shfl_xor(ps, 4);
            ps += __shfl_xor(ps, 8);
            l_run[r] = l_run[r] * __expf(m_run[r] - mnew) + ps;
            m_run[r] = mnew;
        }
    }

    float linv[4];
#pragma unroll
    for (int r = 0; r < 4; ++r) linv[r] = 1.0f / l_run[r];

    // ---------------- pass 2: weights + PV ----------------
    f32x4 acc[4];
#pragma unroll
    for (int s = 0; s < 4; ++s) acc[s] = (f32x4){0.f, 0.f, 0.f, 0.f};

    for (int kt = 0; kt < nkt; ++kt) {
        __syncthreads();
        stage_K(&Kp[(size_t)kt * 4096], Khi, Klo, tid);
        stage_V(&Vp[(size_t)kt * 4096], Vhi, Vlo, tid);
        __syncthreads();

        f32x4 lg[4];
        qk_tile(Khi, Klo, qh, ql, lr, lq, kt == qt, qrow0, kt * 64, lg);
        // normalized weights -> sc  (masked: exp(-1e30 - m) underflows to 0)
#pragma unroll
        for (int s = 0; s < 4; ++s)
#pragma unroll
            for (int r = 0; r < 4; ++r)
                sc[16 * w + lq * 4 + r][16 * s + lr] =
                    __expf(lg[s][r] - m_run[r]) * linv[r];
        __syncthreads();

        // cooperative coalesced float4 store of the weight tile
        {
            const int c4 = (tid & 15) * 4;
            const int r0 = tid >> 4;
#pragma unroll
            for (int i = 0; i < 4; ++i) {
                const int row = r0 + 16 * i;
                float4 w4 = *reinterpret_cast<const float4*>(&sc[row][c4]);
                *reinterpret_cast<float4*>(
                    &wrow[(size_t)row * S_ + kt * 64 + c4]) = w4;
            }
        }

        // P A-fragments from sc: lane holds P[16w+lr][lq*8 + 32c + j]
        bf16x8 pah[2], pal[2];
#pragma unroll
        for (int c = 0; c < 2; ++c) {
            const float* pr = &sc[16 * w + lr][lq * 8 + 32 * c];
            float4 p0 = *reinterpret_cast<const float4*>(pr);
            float4 p1 = *reinterpret_cast<const float4*>(pr + 4);
            float v8[8] = {p0.x, p0.y, p0.z, p0.w, p1.x, p1.y, p1.z, p1.w};
#pragma unroll
            for (int j = 0; j < 8; ++j) {
                __bf16 h0, l0;
                split2(v8[j], h0, l0);
                pah[c][j] = h0; pal[c][j] = l0;
            }
        }

        // PV: acc[s2] over d-subtiles; B-frag = packed V
#pragma unroll
        for (int s2 = 0; s2 < 4; ++s2) {
#pragma unroll
            for (int c = 0; c < 2; ++c) {
                const int kg = 4 * c + lq;
                const int d  = 16 * s2 + lr;
                bf16x8 vh = *reinterpret_cast<const bf16x8*>(Vhi + (kg * 64 + d) * 8);
                bf16x8 vl = *reinterpret_cast<const bf16x8*>(Vlo + (kg * 64 + d) * 8);
                acc[s2] = mfma16(pah[c], vh, acc[s2]);
                acc[s2] = mfma16(pah[c], vl, acc[s2]);
                acc[s2] = mfma16(pal[c], vh, acc[s2]);
            }
        }
    }

    // zero-fill strictly-upper k-tiles of the weights output
    {
        float4 z = {0.f, 0.f, 0.f, 0.f};
        const int c4 = (tid & 15) * 4;
        const int r0 = tid >> 4;
        for (int kt = nkt; kt < S_ / 64; ++kt) {
#pragma unroll
            for (int i = 0; i < 4; ++i) {
                const int row = r0 + 16 * i;
                *reinterpret_cast<float4*>(
                    &wrow[(size_t)row * S_ + kt * 64 + c4]) = z;
            }
        }
    }

    // ctx write, merged-head [B,S,E]: row = q, col = h*64 + 16*s2 + lr
#pragma unroll
    for (int s2 = 0; s2 < 4; ++s2)
#pragma unroll
        for (int r = 0; r < 4; ++r)
            ctx[((size_t)b * S_ + qrow0 + lq * 4 + r) * E_ + h * 64 + 16 * s2 + lr] =
                acc[s2][r];
}

// ---------------------------------------------------------------------------
// Kernel 3: out = ctx @ w_out + b_out. MFMA, same core. Grid (E/128, M/128).
// ---------------------------------------------------------------------------
__global__ __launch_bounds__(256, 2)
void proj_kernel(const float* __restrict__ ctx, const float* __restrict__ wo,
                 const float* __restrict__ bias, float* __restrict__ out) {
    __shared__ __align__(16) __bf16 Ahi[4096], Alo[4096];
    __shared__ __align__(16) __bf16 Bhi[4096], Blo[4096];

    const int bn = blockIdx.x * 128;
    const int bm = blockIdx.y * 128;
    const int tid  = threadIdx.x;
    const int lane = tid & 63;
    const int w    = tid >> 6;
    const int lr   = lane & 15;
    const int lq   = lane >> 4;
    const int wm   = w >> 1, wn = w & 1;

    f32x4 acc[4][4];
#pragma unroll
    for (int mi = 0; mi < 4; ++mi)
#pragma unroll
        for (int ni = 0; ni < 4; ++ni) acc[mi][ni] = (f32x4){0.f, 0.f, 0.f, 0.f};

    gemm_tile_core(ctx + (size_t)bm * E_, E_, wo + bn, E_, E_,
                   Ahi, Alo, Bhi, Blo, acc);

#pragma unroll
    for (int ni = 0; ni < 4; ++ni) {
        const int col = bn + (wn * 4 + ni) * 16 + lr;
        const float bv = bias[col];
#pragma unroll
        for (int mi = 0; mi < 4; ++mi) {
#pragma unroll
            for (int r = 0; r < 4; ++r) {
                const int row = bm + (wm * 4 + mi) * 16 + lq * 4 + r;
                out[(size_t)row * E_ + col] = acc[mi][ni][r] + bv;
            }
        }
    }
}

// ---------------------------------------------------------------------------
extern "C" void kernel_launch(void* const* d_in, const int* in_sizes, int n_in,
                              void* d_out, int out_size, void* d_ws,
                              size_t ws_size, hipStream_t stream) {
    (void)in_sizes; (void)n_in; (void)out_size; (void)ws_size;
    const float* x     = (const float*)d_in[0];
    const float* w_qkv = (const float*)d_in[1];
    const float* b_qkv = (const float*)d_in[2];
    const float* w_out = (const float*)d_in[3];
    const float* b_out = (const float*)d_in[4];

    float* out = (float*)d_out;                       // [B,S,E]
    float* wts = out + (size_t)M_ * E_;               // [B,H,S,S]

    const size_t per = (size_t)B_ * H_ * S_ * D_;     // 8,388,608 floats
    float* Qb  = (float*)d_ws;
    float* Kb  = Qb + per;
    float* Vb  = Kb + per;
    float* ctx = Vb + per;                            // [B,S,E] merged heads

    qkv_kernel<<<dim3(N3 / 128, M_ / 128), 256, 0, stream>>>(
        x, w_qkv, b_qkv, Qb, Kb, Vb);
    attn_kernel<<<dim3(S_ / 64, H_, B_), 256, 0, stream>>>(
        Qb, Kb, Vb, wts, ctx);
    proj_kernel<<<dim3(E_ / 128, M_ / 128), 256, 0, stream>>>(
        ctx, w_out, b_out, out);
}